// Round 5
// baseline (2166.588 us; speedup 1.0000x reference)
//
#include <hip/hip_runtime.h>
#include <math.h>

#define DM     2048
#define NH     16
#define KVHN   4
#define HD     128
#define NSINK  2
#define SEQ    2048
#define BATCH  2
#define SKV    2050   // NSINK + SEQ
#define SCALE_F 0.08838834764831845f
#define NEG_BIG (-1e30f)

typedef _Float16 h8 __attribute__((ext_vector_type(8)));
typedef float f4 __attribute__((ext_vector_type(4)));

__device__ inline void split_f16(float x, _Float16& h, _Float16& l) {
  _Float16 hh = (_Float16)x;          // RNE v_cvt_f16_f32
  h = hh;
  l = (_Float16)(x - (float)hh);      // residual, ~11 extra mantissa bits
}

// ------------------------------------------------------------------
// RoPE cos/sin table: tbl[pos][i] = {cos,sin}(float(pos)*inv_freq[i])
// ------------------------------------------------------------------
__global__ void rope_table_kernel(float* __restrict__ tbl) {
  int pos = blockIdx.x;        // 0..2049
  int i   = threadIdx.x;       // 0..63
  float p    = powf(10000.0f, (float)(2 * i) * (1.0f / 128.0f));
  float invf = 1.0f / p;
  float arg  = (float)pos * invf;          // f32 rounding like reference
  double a = (double)arg;
  tbl[(pos * 64 + i) * 2 + 0] = (float)cos(a);
  tbl[(pos * 64 + i) * 2 + 1] = (float)sin(a);
}

// ------------------------------------------------------------------
// Sink projections: sink_states(2,2048) @ {Wk,Wv}^T -> K/V rows 0..1
// ------------------------------------------------------------------
__global__ void sink_proj_kernel(const float* __restrict__ sink,
                                 const float* __restrict__ Wk,
                                 const float* __restrict__ Wv,
                                 float* __restrict__ Kw,
                                 float* __restrict__ Vw) {
  int t = blockIdx.x * 256 + threadIdx.x;   // 0..2047
  int isV = t >> 10;
  int si  = (t >> 9) & 1;
  int n   = t & 511;
  const float* w = (isV ? Wv : Wk) + (size_t)n * DM;
  const float* x = sink + (size_t)si * DM;
  float sum = 0.f;
  for (int k = 0; k < DM; ++k) sum += x[k] * w[k];
  int kvh = n >> 7, d = n & 127;
  float* dst = isV ? Vw : Kw;
  for (int b = 0; b < BATCH; ++b)
    dst[((size_t)(b * KVHN + kvh) * SKV + si) * HD + d] = sum;
}

// ------------------------------------------------------------------
// f16x3 split MFMA GEMM: C = A(M x K) * W(N x K)^T, near-fp32 accuracy.
// x = hi + lo (fp16 each); acc += ah*bh + ah*bl + al*bh (lo*lo dropped,
// ~2^-22 rel). BM=BN=128, BK=32, 256 thr = 4 waves (2x2 of 64x64), each
// wave 4x4 fragments of v_mfma_f32_16x16x32_f16.
// LDS rows padded to 40 halves (80 B): fragment ds_read_b128 lands 2-way
// bank-aliased (free, m136), not the 8-way of a 64 B stride.
// mode 0: C[m*N+n] ; 1: Q [b][h16][s][d] ; 2/3: K/V [b][kvh4][2+s][d]
// ------------------------------------------------------------------
__global__ __launch_bounds__(256) void gemm_mfma_kernel(
    const float* __restrict__ A, const float* __restrict__ W,
    float* __restrict__ C, int N, int K, int mode) {
  __shared__ _Float16 Ah[128][40];
  __shared__ _Float16 Al[128][40];
  __shared__ _Float16 Bh[128][40];
  __shared__ _Float16 Bl[128][40];
  const int tid  = threadIdx.x;
  const int bm = blockIdx.y * 128, bn = blockIdx.x * 128;
  const int lane = tid & 63, wave = tid >> 6;
  const int wy = wave >> 1, wx = wave & 1;        // 2x2 wave grid, 64x64 each
  const int fr = lane & 15, fk = (lane >> 4) * 8; // fragment row, k-offset
  const int srow = tid >> 1, scol = (tid & 1) * 16;

  f4 acc[4][4];
#pragma unroll
  for (int i = 0; i < 4; ++i)
#pragma unroll
    for (int j = 0; j < 4; ++j) acc[i][j] = (f4){0.f, 0.f, 0.f, 0.f};

  const float* Ag = A + (size_t)(bm + srow) * K + scol;
  const float* Wg = W + (size_t)(bn + srow) * K + scol;

  for (int k0 = 0; k0 < K; k0 += 32) {
    // issue global loads before the barrier (latency hides under prev wait)
    float xa[16], xb[16];
#pragma unroll
    for (int i = 0; i < 4; ++i) {
      *(float4*)&xa[i * 4] = *(const float4*)(Ag + k0 + i * 4);
      *(float4*)&xb[i * 4] = *(const float4*)(Wg + k0 + i * 4);
    }
    __syncthreads();   // previous iteration done reading LDS
    h8 ha0, ha1, la0, la1, hb0, hb1, lb0, lb1;
#pragma unroll
    for (int e = 0; e < 8; ++e) {
      _Float16 h, l;
      split_f16(xa[e], h, l);     ha0[e] = h; la0[e] = l;
      split_f16(xa[e + 8], h, l); ha1[e] = h; la1[e] = l;
      split_f16(xb[e], h, l);     hb0[e] = h; lb0[e] = l;
      split_f16(xb[e + 8], h, l); hb1[e] = h; lb1[e] = l;
    }
    *(h8*)&Ah[srow][scol] = ha0; *(h8*)&Ah[srow][scol + 8] = ha1;
    *(h8*)&Al[srow][scol] = la0; *(h8*)&Al[srow][scol + 8] = la1;
    *(h8*)&Bh[srow][scol] = hb0; *(h8*)&Bh[srow][scol + 8] = hb1;
    *(h8*)&Bl[srow][scol] = lb0; *(h8*)&Bl[srow][scol + 8] = lb1;
    __syncthreads();

    h8 fah[4], fal[4], fbh[4], fbl[4];
#pragma unroll
    for (int f = 0; f < 4; ++f) {
      int ra = wy * 64 + f * 16 + fr;
      int rb = wx * 64 + f * 16 + fr;
      fah[f] = *(const h8*)&Ah[ra][fk];
      fal[f] = *(const h8*)&Al[ra][fk];
      fbh[f] = *(const h8*)&Bh[rb][fk];
      fbl[f] = *(const h8*)&Bl[rb][fk];
    }
#pragma unroll
    for (int i = 0; i < 4; ++i)
#pragma unroll
      for (int j = 0; j < 4; ++j) {
        acc[i][j] = __builtin_amdgcn_mfma_f32_16x16x32_f16(fah[i], fbh[j], acc[i][j], 0, 0, 0);
        acc[i][j] = __builtin_amdgcn_mfma_f32_16x16x32_f16(fah[i], fbl[j], acc[i][j], 0, 0, 0);
        acc[i][j] = __builtin_amdgcn_mfma_f32_16x16x32_f16(fal[i], fbh[j], acc[i][j], 0, 0, 0);
      }
  }

  // epilogue: C/D layout col = lane&15, row = (lane>>4)*4 + reg (m89/m91)
#pragma unroll
  for (int i = 0; i < 4; ++i) {
#pragma unroll
    for (int jj = 0; jj < 4; ++jj) {
      int m = bm + wy * 64 + i * 16 + (lane >> 4) * 4 + jj;
      int bb = m >> 11, s = m & (SEQ - 1);
#pragma unroll
      for (int j = 0; j < 4; ++j) {
        int n = bn + wx * 64 + j * 16 + fr;
        size_t idx;
        if (mode == 0)      idx = (size_t)m * N + n;
        else if (mode == 1) idx = ((size_t)(bb * NH + (n >> 7)) * SEQ + s) * HD + (n & 127);
        else                idx = ((size_t)(bb * KVHN + (n >> 7)) * SKV + (s + NSINK)) * HD + (n & 127);
        C[idx] = acc[i][j][jj];
      }
    }
  }
}

// ------------------------------------------------------------------
// In-place RoPE over Q rows (pos = s+2) and K rows (pos = r<2 ? r : r-2).
// ------------------------------------------------------------------
#define NQROWS (BATCH * NH * SEQ)     // 65536
#define NKROWS (BATCH * KVHN * SKV)   // 16400

__global__ __launch_bounds__(256) void rope_kernel(float* __restrict__ Qw,
                                                   float* __restrict__ Kw,
                                                   const float* __restrict__ tbl) {
  int row = blockIdx.x * 4 + (threadIdx.x >> 6);
  int j   = threadIdx.x & 63;
  float* base;
  int pos;
  if (row < NQROWS) {
    base = Qw + (size_t)row * HD;
    pos  = (row & (SEQ - 1)) + NSINK;
  } else {
    int r = row - NQROWS;
    if (r >= NKROWS) return;
    base = Kw + (size_t)r * HD;
    int rr = r % SKV;
    pos = (rr < NSINK) ? rr : rr - NSINK;
  }
  float x0 = base[j], x1 = base[j + 64];
  const float2* tp = (const float2*)(tbl + (size_t)pos * 128);
  float2 cs0 = tp[j >> 1];
  float2 cs1 = tp[32 + (j >> 1)];
  base[j]      = x0 * cs0.x - x1 * cs0.y;
  base[j + 64] = x1 * cs1.x + x0 * cs1.y;
}

// ------------------------------------------------------------------
// Flash attention, fp32. Block = 256 thr (16x16), 64 q-rows, 32-key tiles.
// Online softmax; causal mask analytic (key j valid iff j<2 || j-2<=q).
// ------------------------------------------------------------------
__global__ __launch_bounds__(256) void attn_kernel(
    const float* __restrict__ Qw, const float* __restrict__ Kw,
    const float* __restrict__ Vw, float* __restrict__ CTX) {
  __shared__ float Qs[64 * 128];
  __shared__ float Ks[32 * 132];   // padded rows (bank spread)
  __shared__ float Vs[32 * 128];
  __shared__ float Ps[64][34];     // padded
  const int tid = threadIdx.x;
  const int q0 = blockIdx.x * 64;
  const int h = blockIdx.y, b = blockIdx.z;
  const int kvh = h >> 2;  // GQA repeat_interleave: head h -> kv head h/4
  const float* Qbase = Qw + ((size_t)((b * NH + h) * SEQ + q0)) * HD;
  const float* Kbase = Kw + (size_t)(b * KVHN + kvh) * SKV * HD;
  const float* Vbase = Vw + (size_t)(b * KVHN + kvh) * SKV * HD;
  {
    const float4* src = (const float4*)Qbase;
    float4* dst = (float4*)Qs;
#pragma unroll
    for (int i = 0; i < 8; ++i) dst[i * 256 + tid] = src[i * 256 + tid];
  }
  const int ty = tid >> 4, tx = tid & 15;
  float o[4][8];
#pragma unroll
  for (int i = 0; i < 4; ++i)
#pragma unroll
    for (int j = 0; j < 8; ++j) o[i][j] = 0.f;
  float mrow[4], lrow[4];
#pragma unroll
  for (int i = 0; i < 4; ++i) { mrow[i] = NEG_BIG; lrow[i] = 0.f; }

  const int kend = q0 + 64 + NSINK;   // <= 2050 always
  const int nt = (kend + 31) >> 5;

  for (int t = 0; t < nt; ++t) {
    const int j0 = t * 32;
    __syncthreads();  // prev iter done with Ks/Vs/Ps
    {
      const float* ksrc = Kbase + (size_t)j0 * HD;
      const float* vsrc = Vbase + (size_t)j0 * HD;
#pragma unroll
      for (int i = 0; i < 4; ++i) {
        int f = i * 256 + tid;        // float4 index 0..1023
        int r = f >> 5, c = f & 31;
        *(float4*)&Ks[r * 132 + c * 4] = *(const float4*)(ksrc + (size_t)f * 4);
        ((float4*)Vs)[f] = *(const float4*)(vsrc + (size_t)f * 4);
      }
    }
    __syncthreads();

    // ---- scores: each thread 4 q-rows x 2 k-cols ----
    float sc0[4], sc1[4];
#pragma unroll
    for (int i = 0; i < 4; ++i) { sc0[i] = 0.f; sc1[i] = 0.f; }
    const float* krow0 = &Ks[(tx * 2 + 0) * 132];
    const float* krow1 = &Ks[(tx * 2 + 1) * 132];
#pragma unroll 8
    for (int d = 0; d < 128; d += 4) {
      float4 k0 = *(const float4*)(krow0 + d);
      float4 k1 = *(const float4*)(krow1 + d);
#pragma unroll
      for (int i = 0; i < 4; ++i) {
        float4 qv = *(const float4*)&Qs[(ty * 4 + i) * 128 + d];
        sc0[i] += qv.x * k0.x + qv.y * k0.y + qv.z * k0.z + qv.w * k0.w;
        sc1[i] += qv.x * k1.x + qv.y * k1.y + qv.z * k1.z + qv.w * k1.w;
      }
    }

    // ---- mask + online softmax (reduce across tx group of 16 lanes) ----
    float alpha[4];
#pragma unroll
    for (int i = 0; i < 4; ++i) {
      int q = q0 + ty * 4 + i;
      int kj0 = j0 + tx * 2, kj1 = kj0 + 1;
      float s0 = sc0[i] * SCALE_F;
      float s1 = sc1[i] * SCALE_F;
      if (!(kj0 < NSINK || (kj0 - NSINK) <= q)) s0 = NEG_BIG;
      if (!(kj1 < NSINK || (kj1 - NSINK) <= q)) s1 = NEG_BIG;
      float mt = fmaxf(s0, s1);
      mt = fmaxf(mt, __shfl_xor(mt, 1));
      mt = fmaxf(mt, __shfl_xor(mt, 2));
      mt = fmaxf(mt, __shfl_xor(mt, 4));
      mt = fmaxf(mt, __shfl_xor(mt, 8));
      float mn = fmaxf(mrow[i], mt);      // finite from tile 0 (sinks)
      alpha[i] = expf(mrow[i] - mn);
      float p0 = expf(s0 - mn);           // masked -> 0
      float p1 = expf(s1 - mn);
      float rs = p0 + p1;
      rs += __shfl_xor(rs, 1);
      rs += __shfl_xor(rs, 2);
      rs += __shfl_xor(rs, 4);
      rs += __shfl_xor(rs, 8);
      lrow[i] = lrow[i] * alpha[i] + rs;
      mrow[i] = mn;
      *(float2*)&Ps[ty * 4 + i][tx * 2] = make_float2(p0, p1);
    }
    __syncthreads();

    // ---- PV: each thread 4 q-rows x 8 d-cols ----
#pragma unroll
    for (int i = 0; i < 4; ++i) {
      float a = alpha[i];
#pragma unroll
      for (int j = 0; j < 8; ++j) o[i][j] *= a;
    }
    for (int k = 0; k < 32; ++k) {
      float4 v0 = *(const float4*)&Vs[k * 128 + tx * 8];
      float4 v1 = *(const float4*)&Vs[k * 128 + tx * 8 + 4];
#pragma unroll
      for (int i = 0; i < 4; ++i) {
        float p = Ps[ty * 4 + i][k];
        o[i][0] = fmaf(p, v0.x, o[i][0]);
        o[i][1] = fmaf(p, v0.y, o[i][1]);
        o[i][2] = fmaf(p, v0.z, o[i][2]);
        o[i][3] = fmaf(p, v0.w, o[i][3]);
        o[i][4] = fmaf(p, v1.x, o[i][4]);
        o[i][5] = fmaf(p, v1.y, o[i][5]);
        o[i][6] = fmaf(p, v1.z, o[i][6]);
        o[i][7] = fmaf(p, v1.w, o[i][7]);
      }
    }
  }

  // ---- finalize: CTX[b][q][h][d] ----
#pragma unroll
  for (int i = 0; i < 4; ++i) {
    float inv = 1.f / lrow[i];
    int q = q0 + ty * 4 + i;
    float* dst = CTX + ((size_t)((b * SEQ + q) * NH + h)) * HD + tx * 8;
    float4 r0 = make_float4(o[i][0] * inv, o[i][1] * inv, o[i][2] * inv, o[i][3] * inv);
    float4 r1 = make_float4(o[i][4] * inv, o[i][5] * inv, o[i][6] * inv, o[i][7] * inv);
    *(float4*)dst = r0;
    *(float4*)(dst + 4) = r1;
  }
}

// ------------------------------------------------------------------
extern "C" void kernel_launch(void* const* d_in, const int* in_sizes, int n_in,
                              void* d_out, int out_size, void* d_ws, size_t ws_size,
                              hipStream_t stream) {
  const float* hs   = (const float*)d_in[0];
  // d_in[1] = attention_mask: deterministically causal -> applied analytically
  const float* Wq   = (const float*)d_in[2];
  const float* Wk   = (const float*)d_in[3];
  const float* Wv   = (const float*)d_in[4];
  const float* Wo   = (const float*)d_in[5];
  const float* sink = (const float*)d_in[6];
  float* out = (float*)d_out;

  // workspace layout (order matters: masked tile-overflow reads from K spill
  // into V, from V into CTX -- all in-bounds, finite, multiplied by p=0)
  float* Qw  = (float*)d_ws;                          // 2*16*2048*128
  float* Kw  = Qw + (size_t)BATCH * NH * SEQ * HD;    // 2*4*2050*128
  float* Vw  = Kw + (size_t)BATCH * KVHN * SKV * HD;  // 2*4*2050*128
  float* CTX = Vw + (size_t)BATCH * KVHN * SKV * HD;  // 2*2048*2048
  float* TBL = CTX + (size_t)BATCH * SEQ * DM;        // 2050*64*2

  rope_table_kernel<<<SKV, 64, 0, stream>>>(TBL);
  sink_proj_kernel<<<8, 256, 0, stream>>>(sink, Wk, Wv, Kw, Vw);
  gemm_mfma_kernel<<<dim3(16, 32), 256, 0, stream>>>(hs, Wq, Qw, 2048, 2048, 1);
  gemm_mfma_kernel<<<dim3(4, 32), 256, 0, stream>>>(hs, Wk, Kw, 512, 2048, 2);
  gemm_mfma_kernel<<<dim3(4, 32), 256, 0, stream>>>(hs, Wv, Vw, 512, 2048, 3);
  rope_kernel<<<20484, 256, 0, stream>>>(Qw, Kw, TBL);
  attn_kernel<<<dim3(32, 16, 2), 256, 0, stream>>>(Qw, Kw, Vw, CTX);
  gemm_mfma_kernel<<<dim3(16, 32), 256, 0, stream>>>(CTX, Wo, out, 2048, 2048, 0);
}

// Round 10
// 814.700 us; speedup vs baseline: 2.6594x; 2.6594x over previous
//
#include <hip/hip_runtime.h>
#include <math.h>

#define DM     2048
#define NH     16
#define KVHN   4
#define HD     128
#define NSINK  2
#define SEQ    2048
#define BATCH  2
#define SKV    2050   // NSINK + SEQ
#define SCALE_F 0.08838834764831845f
#define NEG_BIG (-1e30f)
#define QSCALE  (0.08838834764831845f * 1.4426950408889634f)  // SCALE * log2(e)
#define THRL    3.0f   // defer-max threshold (log2 domain)

typedef _Float16 h8 __attribute__((ext_vector_type(8)));
typedef float f4 __attribute__((ext_vector_type(4)));

__device__ inline void split_f16(float x, _Float16& h, _Float16& l) {
  _Float16 hh = (_Float16)x;
  h = hh;
  l = (_Float16)(x - (float)hh);
}

__device__ inline int f2h2(float a, float b) {
  typedef __fp16 fp16x2 __attribute__((ext_vector_type(2)));
  fp16x2 r = __builtin_amdgcn_cvt_pkrtz(a, b);   // v_cvt_pkrtz_f16_f32
  return __builtin_bit_cast(int, r);
}
__device__ inline h8 mk_h8(int w0, int w1, int w2, int w3) {
  int4 t = make_int4(w0, w1, w2, w3);
  return __builtin_bit_cast(h8, t);
}
__device__ inline float bpermf(int addr, float v) {
  return __builtin_bit_cast(float,
      __builtin_amdgcn_ds_bpermute(addr, __builtin_bit_cast(int, v)));
}

// ------------------------------------------------------------------
// RoPE cos/sin table
// ------------------------------------------------------------------
__global__ void rope_table_kernel(float* __restrict__ tbl) {
  int pos = blockIdx.x;
  int i   = threadIdx.x;
  float p    = powf(10000.0f, (float)(2 * i) * (1.0f / 128.0f));
  float invf = 1.0f / p;
  float arg  = (float)pos * invf;
  double a = (double)arg;
  tbl[(pos * 64 + i) * 2 + 0] = (float)cos(a);
  tbl[(pos * 64 + i) * 2 + 1] = (float)sin(a);
}

// ------------------------------------------------------------------
// Sink projections -> K/V rows 0..1
// ------------------------------------------------------------------
__global__ void sink_proj_kernel(const float* __restrict__ sink,
                                 const float* __restrict__ Wk,
                                 const float* __restrict__ Wv,
                                 float* __restrict__ Kw,
                                 float* __restrict__ Vw) {
  int t = blockIdx.x * 256 + threadIdx.x;
  int isV = t >> 10;
  int si  = (t >> 9) & 1;
  int n   = t & 511;
  const float* w = (isV ? Wv : Wk) + (size_t)n * DM;
  const float* x = sink + (size_t)si * DM;
  float sum = 0.f;
  for (int k = 0; k < DM; ++k) sum += x[k] * w[k];
  int kvh = n >> 7, d = n & 127;
  float* dst = isV ? Vw : Kw;
  for (int b = 0; b < BATCH; ++b)
    dst[((size_t)(b * KVHN + kvh) * SKV + si) * HD + d] = sum;
}

// ------------------------------------------------------------------
// f16x3 split MFMA GEMM (unchanged -- passed round 5, absmax 0.0039)
// ------------------------------------------------------------------
__global__ __launch_bounds__(256) void gemm_mfma_kernel(
    const float* __restrict__ A, const float* __restrict__ W,
    float* __restrict__ C, int N, int K, int mode) {
  __shared__ _Float16 Ah[128][40];
  __shared__ _Float16 Al[128][40];
  __shared__ _Float16 Bh[128][40];
  __shared__ _Float16 Bl[128][40];
  const int tid  = threadIdx.x;
  const int bm = blockIdx.y * 128, bn = blockIdx.x * 128;
  const int lane = tid & 63, wave = tid >> 6;
  const int wy = wave >> 1, wx = wave & 1;
  const int fr = lane & 15, fk = (lane >> 4) * 8;
  const int srow = tid >> 1, scol = (tid & 1) * 16;

  f4 acc[4][4];
#pragma unroll
  for (int i = 0; i < 4; ++i)
#pragma unroll
    for (int j = 0; j < 4; ++j) acc[i][j] = (f4){0.f, 0.f, 0.f, 0.f};

  const float* Ag = A + (size_t)(bm + srow) * K + scol;
  const float* Wg = W + (size_t)(bn + srow) * K + scol;

  for (int k0 = 0; k0 < K; k0 += 32) {
    float xa[16], xb[16];
#pragma unroll
    for (int i = 0; i < 4; ++i) {
      *(float4*)&xa[i * 4] = *(const float4*)(Ag + k0 + i * 4);
      *(float4*)&xb[i * 4] = *(const float4*)(Wg + k0 + i * 4);
    }
    __syncthreads();
    h8 ha0, ha1, la0, la1, hb0, hb1, lb0, lb1;
#pragma unroll
    for (int e = 0; e < 8; ++e) {
      _Float16 h, l;
      split_f16(xa[e], h, l);     ha0[e] = h; la0[e] = l;
      split_f16(xa[e + 8], h, l); ha1[e] = h; la1[e] = l;
      split_f16(xb[e], h, l);     hb0[e] = h; lb0[e] = l;
      split_f16(xb[e + 8], h, l); hb1[e] = h; lb1[e] = l;
    }
    *(h8*)&Ah[srow][scol] = ha0; *(h8*)&Ah[srow][scol + 8] = ha1;
    *(h8*)&Al[srow][scol] = la0; *(h8*)&Al[srow][scol + 8] = la1;
    *(h8*)&Bh[srow][scol] = hb0; *(h8*)&Bh[srow][scol + 8] = hb1;
    *(h8*)&Bl[srow][scol] = lb0; *(h8*)&Bl[srow][scol + 8] = lb1;
    __syncthreads();

    h8 fah[4], fal[4], fbh[4], fbl[4];
#pragma unroll
    for (int f = 0; f < 4; ++f) {
      int ra = wy * 64 + f * 16 + fr;
      int rb = wx * 64 + f * 16 + fr;
      fah[f] = *(const h8*)&Ah[ra][fk];
      fal[f] = *(const h8*)&Al[ra][fk];
      fbh[f] = *(const h8*)&Bh[rb][fk];
      fbl[f] = *(const h8*)&Bl[rb][fk];
    }
#pragma unroll
    for (int i = 0; i < 4; ++i)
#pragma unroll
      for (int j = 0; j < 4; ++j) {
        acc[i][j] = __builtin_amdgcn_mfma_f32_16x16x32_f16(fah[i], fbh[j], acc[i][j], 0, 0, 0);
        acc[i][j] = __builtin_amdgcn_mfma_f32_16x16x32_f16(fah[i], fbl[j], acc[i][j], 0, 0, 0);
        acc[i][j] = __builtin_amdgcn_mfma_f32_16x16x32_f16(fal[i], fbh[j], acc[i][j], 0, 0, 0);
      }
  }

#pragma unroll
  for (int i = 0; i < 4; ++i) {
#pragma unroll
    for (int jj = 0; jj < 4; ++jj) {
      int m = bm + wy * 64 + i * 16 + (lane >> 4) * 4 + jj;
      int bb = m >> 11, s = m & (SEQ - 1);
#pragma unroll
      for (int j = 0; j < 4; ++j) {
        int n = bn + wx * 64 + j * 16 + fr;
        size_t idx;
        if (mode == 0)      idx = (size_t)m * N + n;
        else if (mode == 1) idx = ((size_t)(bb * NH + (n >> 7)) * SEQ + s) * HD + (n & 127);
        else                idx = ((size_t)(bb * KVHN + (n >> 7)) * SKV + (s + NSINK)) * HD + (n & 127);
        C[idx] = acc[i][j][jj];
      }
    }
  }
}

// ------------------------------------------------------------------
// In-place RoPE (unchanged)
// ------------------------------------------------------------------
#define NQROWS (BATCH * NH * SEQ)     // 65536
#define NKROWS (BATCH * KVHN * SKV)   // 16400

__global__ __launch_bounds__(256) void rope_kernel(float* __restrict__ Qw,
                                                   float* __restrict__ Kw,
                                                   const float* __restrict__ tbl) {
  int row = blockIdx.x * 4 + (threadIdx.x >> 6);
  int j   = threadIdx.x & 63;
  float* base;
  int pos;
  if (row < NQROWS) {
    base = Qw + (size_t)row * HD;
    pos  = (row & (SEQ - 1)) + NSINK;
  } else {
    int r = row - NQROWS;
    if (r >= NKROWS) return;
    base = Kw + (size_t)r * HD;
    int rr = r % SKV;
    pos = (rr < NSINK) ? rr : rr - NSINK;
  }
  float x0 = base[j], x1 = base[j + 64];
  const float2* tp = (const float2*)(tbl + (size_t)pos * 128);
  float2 cs0 = tp[j >> 1];
  float2 cs1 = tp[32 + (j >> 1)];
  base[j]      = x0 * cs0.x - x1 * cs0.y;
  base[j + 64] = x1 * cs1.x + x0 * cs1.y;
}

// ------------------------------------------------------------------
// MFMA f16 flash attention. 128 q-rows/block, 4 waves x 32 rows,
// 32-key tiles. Swapped QK^T (scores^T = mfma(K_frag, Q_frag)); P
// assembled to A-frags via cvt_pkrtz + ds_bpermute; V staged transposed.
// log2-domain softmax (SCALE*log2e folded into Q); defer-max THR=3.
// C/D layout (m89): col=lane&15, row=(lane>>4)*4+reg.
// ------------------------------------------------------------------
__global__ __launch_bounds__(256) void attn_mfma_kernel(
    const float* __restrict__ Qw, const float* __restrict__ Kw,
    const float* __restrict__ Vw, float* __restrict__ CTX) {
  __shared__ _Float16 Kl[32][136];   // [key][dim], 272B rows
  __shared__ _Float16 Vt[128][40];   // [dim][key], 80B rows
  const int tid = threadIdx.x;
  const int q0 = blockIdx.x * 128;
  const int h = blockIdx.y, b = blockIdx.z;
  const int kvh = h >> 2;
  const int w = tid >> 6, lane = tid & 63;
  const int c = lane & 15, g = lane >> 4;
  const int Q0 = q0 + w * 32;
  const float* Kbase = Kw + (size_t)(b * KVHN + kvh) * SKV * HD;
  const float* Vbase = Vw + (size_t)(b * KVHN + kvh) * SKV * HD;

  // Q B-fragments (col=q=c, k=dim g*8+32ks), scaled by SCALE*log2e
  h8 Qf[2][4];
  {
    const float* qrow_base = Qw + ((size_t)((b * NH + h) * SEQ + q0 + w * 32)) * HD;
#pragma unroll
    for (int qf = 0; qf < 2; ++qf) {
      const float* qr = qrow_base + (size_t)(qf * 16 + c) * HD + g * 8;
#pragma unroll
      for (int ks = 0; ks < 4; ++ks) {
        float4 x0 = *(const float4*)(qr + ks * 32);
        float4 x1 = *(const float4*)(qr + ks * 32 + 4);
        Qf[qf][ks] = mk_h8(f2h2(x0.x * QSCALE, x0.y * QSCALE),
                           f2h2(x0.z * QSCALE, x0.w * QSCALE),
                           f2h2(x1.x * QSCALE, x1.y * QSCALE),
                           f2h2(x1.z * QSCALE, x1.w * QSCALE));
      }
    }
  }

  f4 acc[2][8];
#pragma unroll
  for (int qf = 0; qf < 2; ++qf)
#pragma unroll
    for (int df = 0; df < 8; ++df) acc[qf][df] = (f4){0.f, 0.f, 0.f, 0.f};
  float m[2] = {NEG_BIG, NEG_BIG};
  float l[2] = {0.f, 0.f};

  const int nt = (q0 + 161) >> 5;   // tiles up to j0 = q0+128
  for (int t = 0; t < nt; ++t) {
    const int j0 = t * 32;
    __syncthreads();   // prev compute done with LDS
    {
      // stage K: [32 keys][128 dims] f32 -> f16
      const int key = tid >> 3, ds = (tid & 7) * 16;
      const float* sk = Kbase + (size_t)(j0 + key) * HD + ds;
      float4 a0 = ((const float4*)sk)[0];
      float4 a1 = ((const float4*)sk)[1];
      float4 a2 = ((const float4*)sk)[2];
      float4 a3 = ((const float4*)sk)[3];
      *(h8*)&Kl[key][ds]     = mk_h8(f2h2(a0.x, a0.y), f2h2(a0.z, a0.w),
                                     f2h2(a1.x, a1.y), f2h2(a1.z, a1.w));
      *(h8*)&Kl[key][ds + 8] = mk_h8(f2h2(a2.x, a2.y), f2h2(a2.z, a2.w),
                                     f2h2(a3.x, a3.y), f2h2(a3.z, a3.w));
      // stage V transposed: Vt[d][key]
      const int d = tid & 127, kg = tid >> 7;
      const float* sv = Vbase + (size_t)(j0 + kg * 16) * HD + d;
      float v[16];
#pragma unroll
      for (int j = 0; j < 16; ++j) v[j] = sv[(size_t)j * HD];
      *(h8*)&Vt[d][kg * 16]     = mk_h8(f2h2(v[0], v[1]),  f2h2(v[2], v[3]),
                                        f2h2(v[4], v[5]),  f2h2(v[6], v[7]));
      *(h8*)&Vt[d][kg * 16 + 8] = mk_h8(f2h2(v[8], v[9]),  f2h2(v[10], v[11]),
                                        f2h2(v[12], v[13]), f2h2(v[14], v[15]));
    }
    __syncthreads();
    if (j0 > Q0 + 33) continue;   // this wave doesn't need these keys

    // K A-frags (row=key=c+16kf, k=dim)
    h8 ka[2][4];
#pragma unroll
    for (int kf = 0; kf < 2; ++kf)
#pragma unroll
      for (int ks = 0; ks < 4; ++ks)
        ka[kf][ks] = *(const h8*)&Kl[kf * 16 + c][g * 8 + ks * 32];

    // scores^T: S[qf][kf], entries: q = Q0+16qf+c, key = j0+16kf+4g+reg
    f4 S[2][2];
#pragma unroll
    for (int qf = 0; qf < 2; ++qf)
#pragma unroll
      for (int kf = 0; kf < 2; ++kf) {
        f4 s = (f4){0.f, 0.f, 0.f, 0.f};
#pragma unroll
        for (int ks = 0; ks < 4; ++ks)
          s = __builtin_amdgcn_mfma_f32_16x16x32_f16(ka[kf][ks], Qf[qf][ks], s, 0, 0, 0);
        S[qf][kf] = s;
      }

    if (j0 + 29 > Q0) {   // diagonal tiles: analytic causal mask
#pragma unroll
      for (int qf = 0; qf < 2; ++qf) {
        int qg = Q0 + qf * 16 + c;
#pragma unroll
        for (int kf = 0; kf < 2; ++kf)
#pragma unroll
          for (int jj = 0; jj < 4; ++jj) {
            int key = j0 + kf * 16 + 4 * g + jj;
            if (!(key < NSINK || (key - NSINK) <= qg)) S[qf][kf][jj] = NEG_BIG;
          }
      }
    }

    // online softmax (log2 domain), per qf; reduce over 4 lane-groups
    float lm[2];
#pragma unroll
    for (int qf = 0; qf < 2; ++qf) {
      float v = fmaxf(fmaxf(fmaxf(S[qf][0][0], S[qf][0][1]), fmaxf(S[qf][0][2], S[qf][0][3])),
                      fmaxf(fmaxf(S[qf][1][0], S[qf][1][1]), fmaxf(S[qf][1][2], S[qf][1][3])));
      v = fmaxf(v, __shfl_xor(v, 16));
      v = fmaxf(v, __shfl_xor(v, 32));
      lm[qf] = v;
    }
    float al0 = 1.f, al1 = 1.f;
    if (!__all((lm[0] - m[0] <= THRL) && (lm[1] - m[1] <= THRL))) {
      float mn0 = fmaxf(m[0], lm[0]), mn1 = fmaxf(m[1], lm[1]);
      al0 = exp2f(m[0] - mn0); al1 = exp2f(m[1] - mn1);
      m[0] = mn0; m[1] = mn1;
#pragma unroll
      for (int reg = 0; reg < 4; ++reg) {
        int addr = (4 * g + reg) * 4;
        float a0 = bpermf(addr, al0);
        float a1 = bpermf(addr, al1);
#pragma unroll
        for (int df = 0; df < 8; ++df) { acc[0][df][reg] *= a0; acc[1][df][reg] *= a1; }
      }
    }

    int pk[2][2][2];
#pragma unroll
    for (int qf = 0; qf < 2; ++qf) {
      float rs = 0.f;
#pragma unroll
      for (int kf = 0; kf < 2; ++kf) {
        float p0 = exp2f(S[qf][kf][0] - m[qf]);
        float p1 = exp2f(S[qf][kf][1] - m[qf]);
        float p2 = exp2f(S[qf][kf][2] - m[qf]);
        float p3 = exp2f(S[qf][kf][3] - m[qf]);
        rs += (p0 + p1) + (p2 + p3);
        pk[qf][kf][0] = f2h2(p0, p1);
        pk[qf][kf][1] = f2h2(p2, p3);
      }
      rs += __shfl_xor(rs, 16);
      rs += __shfl_xor(rs, 32);
      l[qf] = fmaf(l[qf], (qf ? al1 : al0), rs);
    }

    // assemble P A-frags: row=q=c, k=keys 8g..8g+7 (h2 pairs via bpermute)
    const int srcA = (((2 * g) & 3) * 16 + c) * 4;
    const int srcB = (((2 * g + 1) & 3) * 16 + c) * 4;
    const bool hi = (g >> 1) != 0;   // kf of the needed keys
    h8 pa[2];
#pragma unroll
    for (int qf = 0; qf < 2; ++qf) {
      int w0a = __builtin_amdgcn_ds_bpermute(srcA, pk[qf][0][0]);
      int w0b = __builtin_amdgcn_ds_bpermute(srcA, pk[qf][1][0]);
      int w1a = __builtin_amdgcn_ds_bpermute(srcA, pk[qf][0][1]);
      int w1b = __builtin_amdgcn_ds_bpermute(srcA, pk[qf][1][1]);
      int w2a = __builtin_amdgcn_ds_bpermute(srcB, pk[qf][0][0]);
      int w2b = __builtin_amdgcn_ds_bpermute(srcB, pk[qf][1][0]);
      int w3a = __builtin_amdgcn_ds_bpermute(srcB, pk[qf][0][1]);
      int w3b = __builtin_amdgcn_ds_bpermute(srcB, pk[qf][1][1]);
      pa[qf] = mk_h8(hi ? w0b : w0a, hi ? w1b : w1a, hi ? w2b : w2a, hi ? w3b : w3a);
    }

    // PV: ctx[q][d] += P[q][keys] * V[keys][d]
#pragma unroll
    for (int df = 0; df < 8; ++df) {
      h8 vb = *(const h8*)&Vt[c + 16 * df][g * 8];
#pragma unroll
      for (int qf = 0; qf < 2; ++qf)
        acc[qf][df] = __builtin_amdgcn_mfma_f32_16x16x32_f16(pa[qf], vb, acc[qf][df], 0, 0, 0);
    }
  }

  // finalize: D layout row=q=4g+reg(+16qf), col=d=c(+16df); CTX[b][q][h][d]
  float rl0 = 1.f / l[0], rl1 = 1.f / l[1];
#pragma unroll
  for (int qf = 0; qf < 2; ++qf) {
#pragma unroll
    for (int reg = 0; reg < 4; ++reg) {
      int addr = (4 * g + reg) * 4;
      float lv = bpermf(addr, qf ? rl1 : rl0);
      int q = Q0 + qf * 16 + 4 * g + reg;
      float* dst = CTX + ((size_t)((b * SEQ + q) * NH + h)) * HD + c;
#pragma unroll
      for (int df = 0; df < 8; ++df) dst[df * 16] = acc[qf][df][reg] * lv;
    }
  }
}

// ------------------------------------------------------------------
extern "C" void kernel_launch(void* const* d_in, const int* in_sizes, int n_in,
                              void* d_out, int out_size, void* d_ws, size_t ws_size,
                              hipStream_t stream) {
  const float* hs   = (const float*)d_in[0];
  // d_in[1] = attention_mask: deterministically causal -> applied analytically
  const float* Wq   = (const float*)d_in[2];
  const float* Wk   = (const float*)d_in[3];
  const float* Wv   = (const float*)d_in[4];
  const float* Wo   = (const float*)d_in[5];
  const float* sink = (const float*)d_in[6];
  float* out = (float*)d_out;

  // workspace layout (order matters: masked tile-overflow reads from K spill
  // into V, from V into CTX -- all in-bounds, finite, multiplied by p=0)
  float* Qw  = (float*)d_ws;                          // 2*16*2048*128
  float* Kw  = Qw + (size_t)BATCH * NH * SEQ * HD;    // 2*4*2050*128
  float* Vw  = Kw + (size_t)BATCH * KVHN * SKV * HD;  // 2*4*2050*128
  float* CTX = Vw + (size_t)BATCH * KVHN * SKV * HD;  // 2*2048*2048
  float* TBL = CTX + (size_t)BATCH * SEQ * DM;        // 2050*64*2

  rope_table_kernel<<<SKV, 64, 0, stream>>>(TBL);
  sink_proj_kernel<<<8, 256, 0, stream>>>(sink, Wk, Wv, Kw, Vw);
  gemm_mfma_kernel<<<dim3(16, 32), 256, 0, stream>>>(hs, Wq, Qw, 2048, 2048, 1);
  gemm_mfma_kernel<<<dim3(4, 32), 256, 0, stream>>>(hs, Wk, Kw, 512, 2048, 2);
  gemm_mfma_kernel<<<dim3(4, 32), 256, 0, stream>>>(hs, Wv, Vw, 512, 2048, 3);
  rope_kernel<<<20484, 256, 0, stream>>>(Qw, Kw, TBL);
  attn_mfma_kernel<<<dim3(16, 16, 2), 256, 0, stream>>>(Qw, Kw, Vw, CTX);
  gemm_mfma_kernel<<<dim3(16, 32), 256, 0, stream>>>(CTX, Wo, out, 2048, 2048, 0);
}